// Round 1
// baseline (4007.949 us; speedup 1.0000x reference)
//
#include <hip/hip_runtime.h>
#include <math.h>

#define N_NODES 50000
#define N_EDGES 800000
#define D_IN    128
#define D_H     32
#define N_HEADS 8
#define N_GRAPHS 512
#define E_TOT   (N_EDGES + N_NODES)      // 850000 (with self-loops)
#define HDIM    (N_HEADS * D_H)          // 256
#define NEG_SLOPE 0.2f

// ---- monotone float<->uint encoding for atomicMax-based segment max ----
__device__ __forceinline__ unsigned fenc(float f) {
    unsigned u = __float_as_uint(f);
    return (u & 0x80000000u) ? ~u : (u | 0x80000000u);
}
__device__ __forceinline__ float fdec(unsigned u) {
    return __uint_as_float((u & 0x80000000u) ? (u & 0x7FFFFFFFu) : ~u);
}

// ---- sum-reduce edge_weight (fill value = mean) ----
__global__ void k_reduce_sum(const float* __restrict__ ew, float* __restrict__ out, int n) {
    int t = blockIdx.x * blockDim.x + threadIdx.x;
    int stride = gridDim.x * blockDim.x;
    float s = 0.f;
    for (int i = t; i < n; i += stride) s += ew[i];
    for (int m = 1; m < 64; m <<= 1) s += __shfl_xor(s, m);
    __shared__ float ls[4];
    int lane = threadIdx.x & 63, wv = threadIdx.x >> 6;
    if (lane == 0) ls[wv] = s;
    __syncthreads();
    if (threadIdx.x == 0) atomicAdd(out, ls[0] + ls[1] + ls[2] + ls[3]);
}

// ---- generic f32 tiled GEMM: C[M,N] = A[M,K] * B[K,N], row-major ----
#define BM 64
#define BN 64
#define BK 32
__global__ __launch_bounds__(256) void k_gemm(const float* __restrict__ A,
                                              const float* __restrict__ B,
                                              float* __restrict__ C,
                                              int M, int N, int K)
{
    __shared__ float As[BM][BK + 1];
    __shared__ float Bs[BK][BN + 1];
    int row0 = blockIdx.y * BM, col0 = blockIdx.x * BN;
    int tid = threadIdx.x;
    int tx = tid & 15, ty = tid >> 4;
    float acc[4][4] = {};
    for (int k0 = 0; k0 < K; k0 += BK) {
        for (int i = tid; i < BM * BK; i += 256) {
            int r = i >> 5, c = i & 31;            // BK == 32
            int gr = row0 + r;
            As[r][c] = (gr < M) ? A[(size_t)gr * K + k0 + c] : 0.f;
        }
        for (int i = tid; i < BK * BN; i += 256) {
            int r = i >> 6, c = i & 63;            // BN == 64
            int gc = col0 + c;
            Bs[r][c] = (gc < N) ? B[(size_t)(k0 + r) * N + gc] : 0.f;
        }
        __syncthreads();
        #pragma unroll
        for (int kk = 0; kk < BK; ++kk) {
            float av[4], bv[4];
            #pragma unroll
            for (int i = 0; i < 4; ++i) av[i] = As[ty * 4 + i][kk];
            #pragma unroll
            for (int j = 0; j < 4; ++j) bv[j] = Bs[kk][tx * 4 + j];
            #pragma unroll
            for (int i = 0; i < 4; ++i)
                #pragma unroll
                for (int j = 0; j < 4; ++j)
                    acc[i][j] += av[i] * bv[j];
        }
        __syncthreads();
    }
    #pragma unroll
    for (int i = 0; i < 4; ++i) {
        int gr = row0 + ty * 4 + i;
        if (gr >= M) continue;
        #pragma unroll
        for (int j = 0; j < 4; ++j) {
            int gc = col0 + tx * 4 + j;
            if (gc < N) C[(size_t)gr * N + gc] = acc[i][j];
        }
    }
}

// ---- layer-1 edge score: one wave (64 lanes) per edge; 4 elems/lane ----
__global__ __launch_bounds__(256) void k_score1(
    const float* __restrict__ xl, const float* __restrict__ xr,
    const int* __restrict__ ei, const float* __restrict__ ew,
    const float* __restrict__ We, const float* __restrict__ att,
    const float* __restrict__ fillsum,
    float* __restrict__ s_out, unsigned* __restrict__ menc)
{
    int wid = (blockIdx.x * blockDim.x + threadIdx.x) >> 6;
    int lane = threadIdx.x & 63;
    if (wid >= E_TOT) return;
    int e = wid;
    int srcN, dstN; float w;
    if (e < N_EDGES) { srcN = ei[e]; dstN = ei[N_EDGES + e]; w = ew[e]; }
    else { srcN = dstN = e - N_EDGES; w = fillsum[0] * (1.0f / N_EDGES); }
    float4 we4 = ((const float4*)We)[lane];
    float4 at4 = ((const float4*)att)[lane];
    float4 a = ((const float4*)(xl + (size_t)srcN * HDIM))[lane];
    float4 b = ((const float4*)(xr + (size_t)dstN * HDIM))[lane];
    float p = 0.f, z;
    z = a.x + b.x + w * we4.x; z = (z > 0.f) ? z : NEG_SLOPE * z; p += z * at4.x;
    z = a.y + b.y + w * we4.y; z = (z > 0.f) ? z : NEG_SLOPE * z; p += z * at4.y;
    z = a.z + b.z + w * we4.z; z = (z > 0.f) ? z : NEG_SLOPE * z; p += z * at4.z;
    z = a.w + b.w + w * we4.w; z = (z > 0.f) ? z : NEG_SLOPE * z; p += z * at4.w;
    // reduce over the 8 lanes of each head (lane = 8h + j)
    p += __shfl_xor(p, 1);
    p += __shfl_xor(p, 2);
    p += __shfl_xor(p, 4);
    if ((lane & 7) == 0) {
        int h = lane >> 3;
        s_out[(size_t)e * N_HEADS + h] = p;
        atomicMax(&menc[(size_t)dstN * N_HEADS + h], fenc(p));
    }
}

// ---- layer-1 exp + denominator ----
__global__ void k_exp1(float* __restrict__ s, const unsigned* __restrict__ menc,
                       float* __restrict__ den, const int* __restrict__ ei)
{
    int t = blockIdx.x * blockDim.x + threadIdx.x;
    if (t >= E_TOT * N_HEADS) return;
    int e = t >> 3, h = t & 7;
    int dstN = (e < N_EDGES) ? ei[N_EDGES + e] : (e - N_EDGES);
    float m = fdec(menc[dstN * N_HEADS + h]);
    float ex = __expf(s[t] - m);
    s[t] = ex;
    atomicAdd(&den[dstN * N_HEADS + h], ex);
}

// ---- layer-1 aggregate: one wave per edge, 4 f32 atomics per lane ----
__global__ __launch_bounds__(256) void k_agg1(
    const float* __restrict__ xl, const float* __restrict__ sEx,
    const float* __restrict__ den, const int* __restrict__ ei,
    float* __restrict__ out)
{
    int wid = (blockIdx.x * blockDim.x + threadIdx.x) >> 6;
    int lane = threadIdx.x & 63;
    if (wid >= E_TOT) return;
    int e = wid;
    int srcN, dstN;
    if (e < N_EDGES) { srcN = ei[e]; dstN = ei[N_EDGES + e]; }
    else { srcN = dstN = e - N_EDGES; }
    int h = lane >> 3;
    float ex = sEx[(size_t)e * N_HEADS + h];
    float dn = den[dstN * N_HEADS + h];
    float alpha = ex / (dn + 1e-16f);
    float4 a = ((const float4*)(xl + (size_t)srcN * HDIM))[lane];
    float* o = out + (size_t)dstN * HDIM + lane * 4;
    atomicAdd(o + 0, alpha * a.x);
    atomicAdd(o + 1, alpha * a.y);
    atomicAdd(o + 2, alpha * a.z);
    atomicAdd(o + 3, alpha * a.w);
}

// ---- bias + relu in place ----
__global__ void k_bias_relu(float* __restrict__ h, const float* __restrict__ bias,
                            int n, int mask)
{
    int t = blockIdx.x * blockDim.x + threadIdx.x;
    if (t >= n) return;
    float v = h[t] + bias[t & mask];
    h[t] = v > 0.f ? v : 0.f;
}

// ---- layer-2 edge score: one thread per edge (32 channels) ----
__global__ __launch_bounds__(256) void k_score2(
    const float* __restrict__ xl, const float* __restrict__ xr,
    const int* __restrict__ ei, const float* __restrict__ ew,
    const float* __restrict__ We, const float* __restrict__ att,
    const float* __restrict__ fillsum,
    float* __restrict__ s_out, unsigned* __restrict__ menc)
{
    __shared__ float sWe[D_H], sAtt[D_H];
    if (threadIdx.x < D_H) { sWe[threadIdx.x] = We[threadIdx.x]; sAtt[threadIdx.x] = att[threadIdx.x]; }
    __syncthreads();
    int e = blockIdx.x * blockDim.x + threadIdx.x;
    if (e >= E_TOT) return;
    int srcN, dstN; float w;
    if (e < N_EDGES) { srcN = ei[e]; dstN = ei[N_EDGES + e]; w = ew[e]; }
    else { srcN = dstN = e - N_EDGES; w = fillsum[0] * (1.0f / N_EDGES); }
    const float4* A  = (const float4*)(xl + (size_t)srcN * D_H);
    const float4* Bv = (const float4*)(xr + (size_t)dstN * D_H);
    float p = 0.f;
    #pragma unroll
    for (int q = 0; q < D_H / 4; ++q) {
        float4 a = A[q], b = Bv[q];
        float4 we = ((const float4*)sWe)[q], at = ((const float4*)sAtt)[q];
        float z;
        z = a.x + b.x + w * we.x; z = (z > 0.f) ? z : NEG_SLOPE * z; p += z * at.x;
        z = a.y + b.y + w * we.y; z = (z > 0.f) ? z : NEG_SLOPE * z; p += z * at.y;
        z = a.z + b.z + w * we.z; z = (z > 0.f) ? z : NEG_SLOPE * z; p += z * at.z;
        z = a.w + b.w + w * we.w; z = (z > 0.f) ? z : NEG_SLOPE * z; p += z * at.w;
    }
    s_out[e] = p;
    atomicMax(&menc[dstN], fenc(p));
}

// ---- layer-2 exp + denominator ----
__global__ void k_exp2(float* __restrict__ s, const unsigned* __restrict__ menc,
                       float* __restrict__ den, const int* __restrict__ ei)
{
    int e = blockIdx.x * blockDim.x + threadIdx.x;
    if (e >= E_TOT) return;
    int dstN = (e < N_EDGES) ? ei[N_EDGES + e] : (e - N_EDGES);
    float m = fdec(menc[dstN]);
    float ex = __expf(s[e] - m);
    s[e] = ex;
    atomicAdd(&den[dstN], ex);
}

// ---- layer-2 aggregate: 8 threads per edge ----
__global__ __launch_bounds__(256) void k_agg2(
    const float* __restrict__ xl, const float* __restrict__ sEx,
    const float* __restrict__ den, const int* __restrict__ ei,
    float* __restrict__ out)
{
    int gt = blockIdx.x * blockDim.x + threadIdx.x;
    int e = gt >> 3, g = gt & 7;
    if (e >= E_TOT) return;
    int srcN, dstN;
    if (e < N_EDGES) { srcN = ei[e]; dstN = ei[N_EDGES + e]; }
    else { srcN = dstN = e - N_EDGES; }
    float alpha = sEx[e] / (den[dstN] + 1e-16f);
    float4 a = ((const float4*)(xl + (size_t)srcN * D_H))[g];
    float* o = out + (size_t)dstN * D_H + g * 4;
    atomicAdd(o + 0, alpha * a.x);
    atomicAdd(o + 1, alpha * a.y);
    atomicAdd(o + 2, alpha * a.z);
    atomicAdd(o + 3, alpha * a.w);
}

// ---- bias + relu + mean-pool accumulation ----
__global__ void k_pool(const float* __restrict__ out2, const float* __restrict__ b2,
                       const int* __restrict__ batch, float* __restrict__ pool,
                       float* __restrict__ cnt)
{
    int t = blockIdx.x * blockDim.x + threadIdx.x;
    if (t >= N_NODES * D_H) return;
    int i = t >> 5, c = t & 31;
    float v = out2[t] + b2[c];
    v = v > 0.f ? v : 0.f;
    int b = batch[i];
    atomicAdd(&pool[b * D_H + c], v);
    if (c == 0) atomicAdd(&cnt[b], 1.0f);
}

// ---- mean, sigmoid, final FC ----
__global__ void k_final(const float* __restrict__ pool, const float* __restrict__ cnt,
                        const float* __restrict__ Wfc, const float* __restrict__ bfc,
                        float* __restrict__ out)
{
    int b = blockIdx.x * blockDim.x + threadIdx.x;
    if (b >= N_GRAPHS) return;
    float c = cnt[b]; c = c > 1.f ? c : 1.f;
    float acc = 0.f;
    #pragma unroll
    for (int j = 0; j < D_H; ++j) {
        float f = pool[b * D_H + j] / c;
        f = 1.f / (1.f + __expf(-f));
        acc += f * Wfc[j];
    }
    out[b] = acc + bfc[0];
}

extern "C" void kernel_launch(void* const* d_in, const int* in_sizes, int n_in,
                              void* d_out, int out_size, void* d_ws, size_t ws_size,
                              hipStream_t stream)
{
    const float* x    = (const float*)d_in[0];
    const int*   ei   = (const int*)  d_in[1];
    const int*   batch= (const int*)  d_in[2];
    const float* ew   = (const float*)d_in[3];
    const float* Wl1  = (const float*)d_in[4];
    const float* Wr1  = (const float*)d_in[5];
    const float* We1  = (const float*)d_in[6];
    const float* att1 = (const float*)d_in[7];
    const float* b1   = (const float*)d_in[8];
    const float* Wl2  = (const float*)d_in[9];
    const float* Wr2  = (const float*)d_in[10];
    const float* We2  = (const float*)d_in[11];
    const float* att2 = (const float*)d_in[12];
    const float* b2   = (const float*)d_in[13];
    const float* Wfc  = (const float*)d_in[14];
    const float* bfc  = (const float*)d_in[15];
    float* out = (float*)d_out;

    float* ws = (float*)d_ws;
    size_t off = 0;
    auto take = [&](size_t n) -> float* {
        float* p = ws + off;
        off = (off + n + 63) & ~(size_t)63;   // keep 256B alignment for float4
        return p;
    };
    // --- zero-initialized region (one memset covers all of it) ---
    float*    fillsum = take(1);
    unsigned* m1   = (unsigned*)take((size_t)N_NODES * N_HEADS);
    float*    den1 = take((size_t)N_NODES * N_HEADS);
    unsigned* m2   = (unsigned*)take(N_NODES);
    float*    den2 = take(N_NODES);
    float*    pool = take((size_t)N_GRAPHS * D_H);
    float*    cnt  = take(N_GRAPHS);
    float*    out1 = take((size_t)N_NODES * HDIM);
    float*    out2 = take((size_t)N_NODES * D_H);
    size_t zero_elems = off;
    // --- written-before-read buffers ---
    float* xl1 = take((size_t)N_NODES * HDIM);
    float* xr1 = take((size_t)N_NODES * HDIM);
    float* s1  = take((size_t)E_TOT * N_HEADS);
    float* xl2 = take((size_t)N_NODES * D_H);
    float* xr2 = take((size_t)N_NODES * D_H);
    float* s2  = take((size_t)E_TOT);
    (void)ws_size; (void)in_sizes; (void)n_in; (void)out_size;

    hipMemsetAsync(d_ws, 0, zero_elems * sizeof(float), stream);

    // fill value = mean(edge_weight)
    k_reduce_sum<<<512, 256, 0, stream>>>(ew, fillsum, N_EDGES);

    // layer-1 projections
    dim3 g1((HDIM + BN - 1) / BN, (N_NODES + BM - 1) / BM);
    k_gemm<<<g1, 256, 0, stream>>>(x, Wl1, xl1, N_NODES, HDIM, D_IN);
    k_gemm<<<g1, 256, 0, stream>>>(x, Wr1, xr1, N_NODES, HDIM, D_IN);

    // layer-1 edge passes
    int wblocks = (E_TOT + 3) / 4;  // 4 waves per block, 1 edge per wave
    k_score1<<<wblocks, 256, 0, stream>>>(xl1, xr1, ei, ew, We1, att1, fillsum, s1, m1);
    k_exp1<<<(E_TOT * N_HEADS + 255) / 256, 256, 0, stream>>>(s1, m1, den1, ei);
    k_agg1<<<wblocks, 256, 0, stream>>>(xl1, s1, den1, ei, out1);
    k_bias_relu<<<((size_t)N_NODES * HDIM + 255) / 256, 256, 0, stream>>>(out1, b1, N_NODES * HDIM, HDIM - 1);

    // layer-2 projections (input = out1)
    dim3 g2((D_H + BN - 1) / BN, (N_NODES + BM - 1) / BM);
    k_gemm<<<g2, 256, 0, stream>>>(out1, Wl2, xl2, N_NODES, D_H, HDIM);
    k_gemm<<<g2, 256, 0, stream>>>(out1, Wr2, xr2, N_NODES, D_H, HDIM);

    // layer-2 edge passes
    k_score2<<<(E_TOT + 255) / 256, 256, 0, stream>>>(xl2, xr2, ei, ew, We2, att2, fillsum, s2, m2);
    k_exp2<<<(E_TOT + 255) / 256, 256, 0, stream>>>(s2, m2, den2, ei);
    k_agg2<<<((size_t)E_TOT * 8 + 255) / 256, 256, 0, stream>>>(xl2, s2, den2, ei, out2);

    // pooling + final FC
    k_pool<<<(N_NODES * D_H + 255) / 256, 256, 0, stream>>>(out2, b2, batch, pool, cnt);
    k_final<<<(N_GRAPHS + 255) / 256, 256, 0, stream>>>(pool, cnt, Wfc, bfc, out);
}

// Round 2
// 637.423 us; speedup vs baseline: 6.2877x; 6.2877x over previous
//
#include <hip/hip_runtime.h>
#include <math.h>

#define N_NODES 50000
#define N_EDGES 800000
#define D_IN    128
#define D_H     32
#define N_HEADS 8
#define N_GRAPHS 512
#define E_TOT   (N_EDGES + N_NODES)      // 850000 (with self-loops)
#define HDIM    (N_HEADS * D_H)          // 256
#define NEG_SLOPE 0.2f
#define NSCAN_BLK ((N_NODES + 255) / 256)   // 196

// ---- sum-reduce edge_weight (fill value = mean) ----
__global__ void k_reduce_sum(const float* __restrict__ ew, float* __restrict__ out, int n) {
    int t = blockIdx.x * blockDim.x + threadIdx.x;
    int stride = gridDim.x * blockDim.x;
    float s = 0.f;
    for (int i = t; i < n; i += stride) s += ew[i];
    for (int m = 1; m < 64; m <<= 1) s += __shfl_xor(s, m);
    __shared__ float ls[4];
    int lane = threadIdx.x & 63, wv = threadIdx.x >> 6;
    if (lane == 0) ls[wv] = s;
    __syncthreads();
    if (threadIdx.x == 0) atomicAdd(out, ls[0] + ls[1] + ls[2] + ls[3]);
}

// ---- CSR build: histogram of destinations ----
__global__ void k_hist(const int* __restrict__ ei, int* __restrict__ deg) {
    int e = blockIdx.x * blockDim.x + threadIdx.x;
    if (e >= E_TOT) return;
    int dst = (e < N_EDGES) ? ei[N_EDGES + e] : (e - N_EDGES);
    atomicAdd(&deg[dst], 1);
}

// ---- CSR build: 3-kernel exclusive scan over deg[N_NODES] ----
__global__ void k_scan1(const int* __restrict__ deg, int* __restrict__ start,
                        int* __restrict__ bsum) {
    __shared__ int sh[256];
    int i = blockIdx.x * 256 + threadIdx.x;
    int v = (i < N_NODES) ? deg[i] : 0;
    sh[threadIdx.x] = v;
    __syncthreads();
    for (int o = 1; o < 256; o <<= 1) {
        int t = (threadIdx.x >= o) ? sh[threadIdx.x - o] : 0;
        __syncthreads();
        sh[threadIdx.x] += t;
        __syncthreads();
    }
    if (i < N_NODES) start[i] = sh[threadIdx.x] - v;   // exclusive
    if (threadIdx.x == 255) bsum[blockIdx.x] = sh[255];
}
__global__ void k_scan2(int* __restrict__ bsum, int nb) {
    __shared__ int sh[256];
    int v = (threadIdx.x < nb) ? bsum[threadIdx.x] : 0;
    sh[threadIdx.x] = v;
    __syncthreads();
    for (int o = 1; o < 256; o <<= 1) {
        int t = (threadIdx.x >= o) ? sh[threadIdx.x - o] : 0;
        __syncthreads();
        sh[threadIdx.x] += t;
        __syncthreads();
    }
    if (threadIdx.x < nb) bsum[threadIdx.x] = sh[threadIdx.x] - v;  // exclusive
}
__global__ void k_scan3(int* __restrict__ start, const int* __restrict__ bsum) {
    int i = blockIdx.x * 256 + threadIdx.x;
    if (i < N_NODES) start[i] += bsum[blockIdx.x];
}

// ---- CSR build: scatter (src, w) into per-destination segments ----
__global__ void k_scatter(const int* __restrict__ ei, const float* __restrict__ ew,
                          const float* __restrict__ fillsum,
                          const int* __restrict__ start, int* __restrict__ cur,
                          int* __restrict__ csr_src, float* __restrict__ csr_w) {
    int e = blockIdx.x * blockDim.x + threadIdx.x;
    if (e >= E_TOT) return;
    int src, dst; float w;
    if (e < N_EDGES) { src = ei[e]; dst = ei[N_EDGES + e]; w = ew[e]; }
    else { src = dst = e - N_EDGES; w = fillsum[0] * (1.0f / N_EDGES); }
    int pos = start[dst] + atomicAdd(&cur[dst], 1);
    csr_src[pos] = src;
    csr_w[pos] = w;
}

// ---- generic f32 tiled GEMM: C[M,N] = A[M,K] * B[K,N], row-major ----
#define BM 64
#define BN 64
#define BK 32
__global__ __launch_bounds__(256) void k_gemm(const float* __restrict__ A,
                                              const float* __restrict__ B,
                                              float* __restrict__ C,
                                              int M, int N, int K)
{
    __shared__ float As[BM][BK + 1];
    __shared__ float Bs[BK][BN + 1];
    int row0 = blockIdx.y * BM, col0 = blockIdx.x * BN;
    int tid = threadIdx.x;
    int tx = tid & 15, ty = tid >> 4;
    float acc[4][4] = {};
    for (int k0 = 0; k0 < K; k0 += BK) {
        for (int i = tid; i < BM * BK; i += 256) {
            int r = i >> 5, c = i & 31;
            int gr = row0 + r;
            As[r][c] = (gr < M) ? A[(size_t)gr * K + k0 + c] : 0.f;
        }
        for (int i = tid; i < BK * BN; i += 256) {
            int r = i >> 6, c = i & 63;
            int gc = col0 + c;
            Bs[r][c] = (gc < N) ? B[(size_t)(k0 + r) * N + gc] : 0.f;
        }
        __syncthreads();
        #pragma unroll
        for (int kk = 0; kk < BK; ++kk) {
            float av[4], bv[4];
            #pragma unroll
            for (int i = 0; i < 4; ++i) av[i] = As[ty * 4 + i][kk];
            #pragma unroll
            for (int j = 0; j < 4; ++j) bv[j] = Bs[kk][tx * 4 + j];
            #pragma unroll
            for (int i = 0; i < 4; ++i)
                #pragma unroll
                for (int j = 0; j < 4; ++j)
                    acc[i][j] += av[i] * bv[j];
        }
        __syncthreads();
    }
    #pragma unroll
    for (int i = 0; i < 4; ++i) {
        int gr = row0 + ty * 4 + i;
        if (gr >= M) continue;
        #pragma unroll
        for (int j = 0; j < 4; ++j) {
            int gc = col0 + tx * 4 + j;
            if (gc < N) C[(size_t)gr * N + gc] = acc[i][j];
        }
    }
}

// ---- fused layer-1: score + online softmax + aggregate + bias + relu ----
// one wave (64 lanes) per node; lane owns 4 channels, head h = lane>>3
__global__ __launch_bounds__(256) void k_gat1(
    const float* __restrict__ xl, const float* __restrict__ xr,
    const int* __restrict__ start, const int* __restrict__ deg,
    const int* __restrict__ csr_src, const float* __restrict__ csr_w,
    const float* __restrict__ We, const float* __restrict__ att,
    const float* __restrict__ b1, float* __restrict__ out1)
{
    int wid = (blockIdx.x * blockDim.x + threadIdx.x) >> 6;
    int lane = threadIdx.x & 63;
    if (wid >= N_NODES) return;
    int i = wid;
    float4 we4 = ((const float4*)We)[lane];
    float4 at4 = ((const float4*)att)[lane];
    float4 xr4 = ((const float4*)(xr + (size_t)i * HDIM))[lane];
    int s0 = start[i], dg = deg[i];
    float m = -INFINITY, d = 0.f;
    float4 acc = {0.f, 0.f, 0.f, 0.f};
    for (int j = 0; j < dg; ++j) {
        int src = csr_src[s0 + j];
        float w = csr_w[s0 + j];
        float4 a = ((const float4*)(xl + (size_t)src * HDIM))[lane];
        float z, p = 0.f;
        z = a.x + xr4.x + w * we4.x; z = (z > 0.f) ? z : NEG_SLOPE * z; p += z * at4.x;
        z = a.y + xr4.y + w * we4.y; z = (z > 0.f) ? z : NEG_SLOPE * z; p += z * at4.y;
        z = a.z + xr4.z + w * we4.z; z = (z > 0.f) ? z : NEG_SLOPE * z; p += z * at4.z;
        z = a.w + xr4.w + w * we4.w; z = (z > 0.f) ? z : NEG_SLOPE * z; p += z * at4.w;
        // reduce over the 8 lanes of this head
        p += __shfl_xor(p, 1);
        p += __shfl_xor(p, 2);
        p += __shfl_xor(p, 4);
        float nm = fmaxf(m, p);
        float sc = __expf(m - nm);      // 0 on first edge (m = -inf)
        float pe = __expf(p - nm);
        d = d * sc + pe;
        acc.x = acc.x * sc + pe * a.x;
        acc.y = acc.y * sc + pe * a.y;
        acc.z = acc.z * sc + pe * a.z;
        acc.w = acc.w * sc + pe * a.w;
        m = nm;
    }
    float inv = 1.f / (d + 1e-16f);
    float4 b4 = ((const float4*)b1)[lane];
    float4 o;
    o.x = fmaxf(acc.x * inv + b4.x, 0.f);
    o.y = fmaxf(acc.y * inv + b4.y, 0.f);
    o.z = fmaxf(acc.z * inv + b4.z, 0.f);
    o.w = fmaxf(acc.w * inv + b4.w, 0.f);
    ((float4*)(out1 + (size_t)i * HDIM))[lane] = o;
}

// ---- fused layer-2: score + online softmax + aggregate + bias + relu + pool ----
// 8 threads per node; thread owns 4 of the 32 channels
__global__ __launch_bounds__(256) void k_gat2(
    const float* __restrict__ xl, const float* __restrict__ xr,
    const int* __restrict__ start, const int* __restrict__ deg,
    const int* __restrict__ csr_src, const float* __restrict__ csr_w,
    const float* __restrict__ We, const float* __restrict__ att,
    const float* __restrict__ b2, const int* __restrict__ batch,
    float* __restrict__ pool, float* __restrict__ cnt)
{
    int gt = blockIdx.x * blockDim.x + threadIdx.x;
    int i = gt >> 3, g = gt & 7;
    if (i >= N_NODES) return;
    float4 we4 = ((const float4*)We)[g];
    float4 at4 = ((const float4*)att)[g];
    float4 xr4 = ((const float4*)(xr + (size_t)i * D_H))[g];
    int s0 = start[i], dg = deg[i];
    float m = -INFINITY, d = 0.f;
    float4 acc = {0.f, 0.f, 0.f, 0.f};
    for (int j = 0; j < dg; ++j) {
        int src = csr_src[s0 + j];
        float w = csr_w[s0 + j];
        float4 a = ((const float4*)(xl + (size_t)src * D_H))[g];
        float z, p = 0.f;
        z = a.x + xr4.x + w * we4.x; z = (z > 0.f) ? z : NEG_SLOPE * z; p += z * at4.x;
        z = a.y + xr4.y + w * we4.y; z = (z > 0.f) ? z : NEG_SLOPE * z; p += z * at4.y;
        z = a.z + xr4.z + w * we4.z; z = (z > 0.f) ? z : NEG_SLOPE * z; p += z * at4.z;
        z = a.w + xr4.w + w * we4.w; z = (z > 0.f) ? z : NEG_SLOPE * z; p += z * at4.w;
        p += __shfl_xor(p, 1);
        p += __shfl_xor(p, 2);
        p += __shfl_xor(p, 4);
        float nm = fmaxf(m, p);
        float sc = __expf(m - nm);
        float pe = __expf(p - nm);
        d = d * sc + pe;
        acc.x = acc.x * sc + pe * a.x;
        acc.y = acc.y * sc + pe * a.y;
        acc.z = acc.z * sc + pe * a.z;
        acc.w = acc.w * sc + pe * a.w;
        m = nm;
    }
    float inv = 1.f / (d + 1e-16f);
    float4 b4 = ((const float4*)b2)[g];
    float vx = fmaxf(acc.x * inv + b4.x, 0.f);
    float vy = fmaxf(acc.y * inv + b4.y, 0.f);
    float vz = fmaxf(acc.z * inv + b4.z, 0.f);
    float vw = fmaxf(acc.w * inv + b4.w, 0.f);
    int b = batch[i];
    float* o = pool + (size_t)b * D_H + g * 4;
    atomicAdd(o + 0, vx);
    atomicAdd(o + 1, vy);
    atomicAdd(o + 2, vz);
    atomicAdd(o + 3, vw);
    if (g == 0) atomicAdd(&cnt[b], 1.0f);
}

// ---- mean, sigmoid, final FC ----
__global__ void k_final(const float* __restrict__ pool, const float* __restrict__ cnt,
                        const float* __restrict__ Wfc, const float* __restrict__ bfc,
                        float* __restrict__ out)
{
    int b = blockIdx.x * blockDim.x + threadIdx.x;
    if (b >= N_GRAPHS) return;
    float c = cnt[b]; c = c > 1.f ? c : 1.f;
    float acc = 0.f;
    #pragma unroll
    for (int j = 0; j < D_H; ++j) {
        float f = pool[b * D_H + j] / c;
        f = 1.f / (1.f + __expf(-f));
        acc += f * Wfc[j];
    }
    out[b] = acc + bfc[0];
}

extern "C" void kernel_launch(void* const* d_in, const int* in_sizes, int n_in,
                              void* d_out, int out_size, void* d_ws, size_t ws_size,
                              hipStream_t stream)
{
    const float* x    = (const float*)d_in[0];
    const int*   ei   = (const int*)  d_in[1];
    const int*   batch= (const int*)  d_in[2];
    const float* ew   = (const float*)d_in[3];
    const float* Wl1  = (const float*)d_in[4];
    const float* Wr1  = (const float*)d_in[5];
    const float* We1  = (const float*)d_in[6];
    const float* att1 = (const float*)d_in[7];
    const float* b1   = (const float*)d_in[8];
    const float* Wl2  = (const float*)d_in[9];
    const float* Wr2  = (const float*)d_in[10];
    const float* We2  = (const float*)d_in[11];
    const float* att2 = (const float*)d_in[12];
    const float* b2   = (const float*)d_in[13];
    const float* Wfc  = (const float*)d_in[14];
    const float* bfc  = (const float*)d_in[15];
    float* out = (float*)d_out;

    float* ws = (float*)d_ws;
    size_t off = 0;
    auto take = [&](size_t n) -> float* {
        float* p = ws + off;
        off = (off + n + 63) & ~(size_t)63;   // keep 256B alignment for float4
        return p;
    };
    // --- zero-initialized region (one memset covers all of it) ---
    float* fillsum = take(1);
    int*   deg  = (int*)take(N_NODES);
    int*   cur  = (int*)take(N_NODES);
    float* cnt  = take(N_GRAPHS);
    float* pool = take((size_t)N_GRAPHS * D_H);
    size_t zero_elems = off;
    // --- written-before-read buffers ---
    int*   start   = (int*)take(N_NODES);
    int*   bsum    = (int*)take(256);
    int*   csr_src = (int*)take(E_TOT);
    float* csr_w   = take(E_TOT);
    float* xl1 = take((size_t)N_NODES * HDIM);
    float* xr1 = take((size_t)N_NODES * HDIM);
    float* out1 = take((size_t)N_NODES * HDIM);
    float* xl2 = take((size_t)N_NODES * D_H);
    float* xr2 = take((size_t)N_NODES * D_H);
    (void)ws_size; (void)in_sizes; (void)n_in; (void)out_size;

    hipMemsetAsync(d_ws, 0, zero_elems * sizeof(float), stream);

    // fill value = mean(edge_weight)
    k_reduce_sum<<<512, 256, 0, stream>>>(ew, fillsum, N_EDGES);

    // CSR build (destination-sorted)
    k_hist<<<(E_TOT + 255) / 256, 256, 0, stream>>>(ei, deg);
    k_scan1<<<NSCAN_BLK, 256, 0, stream>>>(deg, start, bsum);
    k_scan2<<<1, 256, 0, stream>>>(bsum, NSCAN_BLK);
    k_scan3<<<NSCAN_BLK, 256, 0, stream>>>(start, bsum);
    k_scatter<<<(E_TOT + 255) / 256, 256, 0, stream>>>(ei, ew, fillsum, start, cur, csr_src, csr_w);

    // layer-1 projections
    dim3 g1((HDIM + BN - 1) / BN, (N_NODES + BM - 1) / BM);
    k_gemm<<<g1, 256, 0, stream>>>(x, Wl1, xl1, N_NODES, HDIM, D_IN);
    k_gemm<<<g1, 256, 0, stream>>>(x, Wr1, xr1, N_NODES, HDIM, D_IN);

    // fused layer-1 edge phase (one wave per node)
    k_gat1<<<(N_NODES * 64 + 255) / 256, 256, 0, stream>>>(
        xl1, xr1, start, deg, csr_src, csr_w, We1, att1, b1, out1);

    // layer-2 projections (input = out1)
    dim3 g2((D_H + BN - 1) / BN, (N_NODES + BM - 1) / BM);
    k_gemm<<<g2, 256, 0, stream>>>(out1, Wl2, xl2, N_NODES, D_H, HDIM);
    k_gemm<<<g2, 256, 0, stream>>>(out1, Wr2, xr2, N_NODES, D_H, HDIM);

    // fused layer-2 edge phase + pooling accumulation (8 threads per node)
    k_gat2<<<((size_t)N_NODES * 8 + 255) / 256, 256, 0, stream>>>(
        xl2, xr2, start, deg, csr_src, csr_w, We2, att2, b2, batch, pool, cnt);

    // final FC
    k_final<<<(N_GRAPHS + 255) / 256, 256, 0, stream>>>(pool, cnt, Wfc, bfc, out);
}

// Round 3
// 381.886 us; speedup vs baseline: 10.4952x; 1.6691x over previous
//
#include <hip/hip_runtime.h>
#include <math.h>

#define N_NODES 50000
#define N_EDGES 800000
#define D_IN    128
#define D_H     32
#define N_HEADS 8
#define N_GRAPHS 512
#define E_TOT   (N_EDGES + N_NODES)      // 850000 (with self-loops)
#define HDIM    (N_HEADS * D_H)          // 256
#define NEG_SLOPE 0.2f
#define NSCAN_BLK ((N_NODES + 255) / 256)   // 196

typedef short bfrag8 __attribute__((ext_vector_type(8)));   // 8 bf16 = 4 VGPRs
typedef float f32x4 __attribute__((ext_vector_type(4)));

// ---- bf16 helpers ----
__device__ __forceinline__ float b2f(unsigned short u) {
    return __uint_as_float(((unsigned)u) << 16);
}
__device__ __forceinline__ unsigned short f2b(float x) {
    unsigned u = __float_as_uint(x);
    unsigned r = u + 0x7FFFu + ((u >> 16) & 1u);   // round-to-nearest-even
    return (unsigned short)(r >> 16);
}
__device__ __forceinline__ float4 u4f(ushort4 u) {
    float4 f;
    f.x = b2f(u.x); f.y = b2f(u.y); f.z = b2f(u.z); f.w = b2f(u.w);
    return f;
}

// ---- sum-reduce edge_weight (fill value = mean) ----
__global__ void k_reduce_sum(const float* __restrict__ ew, float* __restrict__ out, int n) {
    int t = blockIdx.x * blockDim.x + threadIdx.x;
    int stride = gridDim.x * blockDim.x;
    float s = 0.f;
    for (int i = t; i < n; i += stride) s += ew[i];
    for (int m = 1; m < 64; m <<= 1) s += __shfl_xor(s, m);
    __shared__ float ls[4];
    int lane = threadIdx.x & 63, wv = threadIdx.x >> 6;
    if (lane == 0) ls[wv] = s;
    __syncthreads();
    if (threadIdx.x == 0) atomicAdd(out, ls[0] + ls[1] + ls[2] + ls[3]);
}

// ---- CSR build ----
__global__ void k_hist(const int* __restrict__ ei, int* __restrict__ deg) {
    int e = blockIdx.x * blockDim.x + threadIdx.x;
    if (e >= E_TOT) return;
    int dst = (e < N_EDGES) ? ei[N_EDGES + e] : (e - N_EDGES);
    atomicAdd(&deg[dst], 1);
}
__global__ void k_scan1(const int* __restrict__ deg, int* __restrict__ start,
                        int* __restrict__ bsum) {
    __shared__ int sh[256];
    int i = blockIdx.x * 256 + threadIdx.x;
    int v = (i < N_NODES) ? deg[i] : 0;
    sh[threadIdx.x] = v;
    __syncthreads();
    for (int o = 1; o < 256; o <<= 1) {
        int t = (threadIdx.x >= o) ? sh[threadIdx.x - o] : 0;
        __syncthreads();
        sh[threadIdx.x] += t;
        __syncthreads();
    }
    if (i < N_NODES) start[i] = sh[threadIdx.x] - v;
    if (threadIdx.x == 255) bsum[blockIdx.x] = sh[255];
}
__global__ void k_scan2(int* __restrict__ bsum, int nb) {
    __shared__ int sh[256];
    int v = (threadIdx.x < nb) ? bsum[threadIdx.x] : 0;
    sh[threadIdx.x] = v;
    __syncthreads();
    for (int o = 1; o < 256; o <<= 1) {
        int t = (threadIdx.x >= o) ? sh[threadIdx.x - o] : 0;
        __syncthreads();
        sh[threadIdx.x] += t;
        __syncthreads();
    }
    if (threadIdx.x < nb) bsum[threadIdx.x] = sh[threadIdx.x] - v;
}
__global__ void k_scan3(int* __restrict__ start, const int* __restrict__ bsum) {
    int i = blockIdx.x * 256 + threadIdx.x;
    if (i < N_NODES) start[i] += bsum[blockIdx.x];
}
__global__ void k_scatter(const int* __restrict__ ei, const float* __restrict__ ew,
                          const float* __restrict__ fillsum,
                          const int* __restrict__ start, int* __restrict__ cur,
                          int* __restrict__ csr_src, float* __restrict__ csr_w) {
    int e = blockIdx.x * blockDim.x + threadIdx.x;
    if (e >= E_TOT) return;
    int src, dst; float w;
    if (e < N_EDGES) { src = ei[e]; dst = ei[N_EDGES + e]; w = ew[e]; }
    else { src = dst = e - N_EDGES; w = fillsum[0] * (1.0f / N_EDGES); }
    int pos = start[dst] + atomicAdd(&cur[dst], 1);
    csr_src[pos] = src;
    csr_w[pos] = w;
}

// ---- casts / weight prep ----
__global__ void k_cast_x(const float* __restrict__ x, unsigned short* __restrict__ xb, int n4) {
    int t = blockIdx.x * blockDim.x + threadIdx.x;
    if (t >= n4) return;
    float4 v = ((const float4*)x)[t];
    ushort4 o;
    o.x = f2b(v.x); o.y = f2b(v.y); o.z = f2b(v.z); o.w = f2b(v.w);
    ((ushort4*)xb)[t] = o;
}
// Wt1[c][k] = bf16( c<256 ? Wl1[k][c] : Wr1[k][c-256] ), c in [0,512), k in [0,128)
__global__ void k_prep_w1(const float* __restrict__ Wl, const float* __restrict__ Wr,
                          unsigned short* __restrict__ Wt) {
    int t = blockIdx.x * blockDim.x + threadIdx.x;   // t = c*128 + k
    if (t >= 512 * 128) return;
    int c = t >> 7, k = t & 127;
    float v = (c < 256) ? Wl[k * 256 + c] : Wr[k * 256 + (c - 256)];
    Wt[t] = f2b(v);
}
// Wt2[c][k] = bf16( c<32 ? Wl2[k][c] : Wr2[k][c-32] ), c in [0,64), k in [0,256)
__global__ void k_prep_w2(const float* __restrict__ Wl, const float* __restrict__ Wr,
                          unsigned short* __restrict__ Wt) {
    int t = blockIdx.x * blockDim.x + threadIdx.x;   // t = c*256 + k
    if (t >= 64 * 256) return;
    int c = t >> 8, k = t & 255;
    float v = (c < 32) ? Wl[k * 32 + c] : Wr[k * 32 + (c - 32)];
    Wt[t] = f2b(v);
}

// ---- bf16 MFMA GEMM: C[M,N] = A[M,KC] * Bt[N,KC]^T, all bf16 row-major ----
// 64x64 tile, full-K LDS staging, 4 waves in 2x2, each wave 32x32 (2x2 frags)
template <int KC>
__global__ __launch_bounds__(256) void k_gemm_bf16(
    const unsigned short* __restrict__ A, const unsigned short* __restrict__ Bt,
    unsigned short* __restrict__ C, int M, int N)
{
    __shared__ unsigned short A_lds[64][KC + 8];
    __shared__ unsigned short B_lds[64][KC + 8];
    int row0 = blockIdx.y * 64, col0 = blockIdx.x * 64;
    int tid = threadIdx.x;
    const int CPR = KC / 8;     // 16B chunks per row
    for (int idx = tid; idx < 64 * CPR; idx += 256) {
        int r = idx / CPR, ch = idx % CPR;
        int gr = row0 + r;
        uint4 v = {0u, 0u, 0u, 0u};
        if (gr < M) v = *(const uint4*)(A + (size_t)gr * KC + ch * 8);
        *(uint4*)&A_lds[r][ch * 8] = v;
    }
    for (int idx = tid; idx < 64 * CPR; idx += 256) {
        int r = idx / CPR, ch = idx % CPR;
        uint4 v = *(const uint4*)(Bt + (size_t)(col0 + r) * KC + ch * 8);
        *(uint4*)&B_lds[r][ch * 8] = v;
    }
    __syncthreads();

    int wid = tid >> 6, lane = tid & 63;
    int wy = wid >> 1, wx = wid & 1;
    int lr = lane & 15, lh = lane >> 4;
    f32x4 acc[2][2] = {};
    #pragma unroll
    for (int k0 = 0; k0 < KC; k0 += 32) {
        bfrag8 a0 = *(const bfrag8*)&A_lds[32 * wy + lr][k0 + lh * 8];
        bfrag8 a1 = *(const bfrag8*)&A_lds[32 * wy + 16 + lr][k0 + lh * 8];
        bfrag8 b0 = *(const bfrag8*)&B_lds[32 * wx + lr][k0 + lh * 8];
        bfrag8 b1 = *(const bfrag8*)&B_lds[32 * wx + 16 + lr][k0 + lh * 8];
        acc[0][0] = __builtin_amdgcn_mfma_f32_16x16x32_bf16(a0, b0, acc[0][0], 0, 0, 0);
        acc[0][1] = __builtin_amdgcn_mfma_f32_16x16x32_bf16(a0, b1, acc[0][1], 0, 0, 0);
        acc[1][0] = __builtin_amdgcn_mfma_f32_16x16x32_bf16(a1, b0, acc[1][0], 0, 0, 0);
        acc[1][1] = __builtin_amdgcn_mfma_f32_16x16x32_bf16(a1, b1, acc[1][1], 0, 0, 0);
    }
    #pragma unroll
    for (int mt = 0; mt < 2; ++mt) {
        #pragma unroll
        for (int nt = 0; nt < 2; ++nt) {
            #pragma unroll
            for (int r = 0; r < 4; ++r) {
                int row = row0 + 32 * wy + 16 * mt + lh * 4 + r;
                if (row < M)
                    C[(size_t)row * N + col0 + 32 * wx + 16 * nt + lr] = f2b(acc[mt][nt][r]);
            }
        }
    }
}

// ---- fused layer-1: one wave per node; lane owns 4 of 256 channels ----
// xlr: [N][512] bf16, cols 0..255 = xl, 256..511 = xr. out1: [N][256] bf16.
__global__ __launch_bounds__(256) void k_gat1(
    const unsigned short* __restrict__ xlr,
    const int* __restrict__ start, const int* __restrict__ deg,
    const int* __restrict__ csr_src, const float* __restrict__ csr_w,
    const float* __restrict__ We, const float* __restrict__ att,
    const float* __restrict__ b1, unsigned short* __restrict__ out1)
{
    int wid = (blockIdx.x * blockDim.x + threadIdx.x) >> 6;
    int lane = threadIdx.x & 63;
    if (wid >= N_NODES) return;
    float4 we4 = ((const float4*)We)[lane];
    float4 at4 = ((const float4*)att)[lane];
    float4 xr4 = u4f(*(const ushort4*)(xlr + (size_t)wid * 512 + 256 + 4 * lane));
    int s0 = start[wid], dg = deg[wid];
    float m = -INFINITY, d = 0.f;
    float4 acc = {0.f, 0.f, 0.f, 0.f};
    int src = csr_src[s0];
    float w = csr_w[s0];
    ushort4 raw = *(const ushort4*)(xlr + (size_t)src * 512 + 4 * lane);
    for (int j = 0; j < dg; ++j) {
        ushort4 craw = raw;
        float cw = w;
        if (j + 1 < dg) {
            src = csr_src[s0 + j + 1];
            w = csr_w[s0 + j + 1];
            raw = *(const ushort4*)(xlr + (size_t)src * 512 + 4 * lane);
        }
        float4 a = u4f(craw);
        float z, p = 0.f;
        z = a.x + xr4.x + cw * we4.x; z = (z > 0.f) ? z : NEG_SLOPE * z; p += z * at4.x;
        z = a.y + xr4.y + cw * we4.y; z = (z > 0.f) ? z : NEG_SLOPE * z; p += z * at4.y;
        z = a.z + xr4.z + cw * we4.z; z = (z > 0.f) ? z : NEG_SLOPE * z; p += z * at4.z;
        z = a.w + xr4.w + cw * we4.w; z = (z > 0.f) ? z : NEG_SLOPE * z; p += z * at4.w;
        p += __shfl_xor(p, 1);
        p += __shfl_xor(p, 2);
        p += __shfl_xor(p, 4);
        float nm = fmaxf(m, p);
        float sc = __expf(m - nm);
        float pe = __expf(p - nm);
        d = d * sc + pe;
        acc.x = acc.x * sc + pe * a.x;
        acc.y = acc.y * sc + pe * a.y;
        acc.z = acc.z * sc + pe * a.z;
        acc.w = acc.w * sc + pe * a.w;
        m = nm;
    }
    float inv = 1.f / (d + 1e-16f);
    float4 b4 = ((const float4*)b1)[lane];
    ushort4 o;
    o.x = f2b(fmaxf(acc.x * inv + b4.x, 0.f));
    o.y = f2b(fmaxf(acc.y * inv + b4.y, 0.f));
    o.z = f2b(fmaxf(acc.z * inv + b4.z, 0.f));
    o.w = f2b(fmaxf(acc.w * inv + b4.w, 0.f));
    *(ushort4*)(out1 + (size_t)wid * 256 + 4 * lane) = o;
}

// ---- fused layer-2 + pool: 8 threads per node; thread owns 4 of 32 channels ----
// xlr2: [N][64] bf16, cols 0..31 = xl, 32..63 = xr.
__global__ __launch_bounds__(256) void k_gat2(
    const unsigned short* __restrict__ xlr2,
    const int* __restrict__ start, const int* __restrict__ deg,
    const int* __restrict__ csr_src, const float* __restrict__ csr_w,
    const float* __restrict__ We, const float* __restrict__ att,
    const float* __restrict__ b2, const int* __restrict__ batch,
    float* __restrict__ pool, float* __restrict__ cnt)
{
    int gt = blockIdx.x * blockDim.x + threadIdx.x;
    int i = gt >> 3, g = gt & 7;
    if (i >= N_NODES) return;
    float4 we4 = ((const float4*)We)[g];
    float4 at4 = ((const float4*)att)[g];
    float4 xr4 = u4f(*(const ushort4*)(xlr2 + (size_t)i * 64 + 32 + 4 * g));
    int s0 = start[i], dg = deg[i];
    float m = -INFINITY, d = 0.f;
    float4 acc = {0.f, 0.f, 0.f, 0.f};
    int src = csr_src[s0];
    float w = csr_w[s0];
    ushort4 raw = *(const ushort4*)(xlr2 + (size_t)src * 64 + 4 * g);
    for (int j = 0; j < dg; ++j) {
        ushort4 craw = raw;
        float cw = w;
        if (j + 1 < dg) {
            src = csr_src[s0 + j + 1];
            w = csr_w[s0 + j + 1];
            raw = *(const ushort4*)(xlr2 + (size_t)src * 64 + 4 * g);
        }
        float4 a = u4f(craw);
        float z, p = 0.f;
        z = a.x + xr4.x + cw * we4.x; z = (z > 0.f) ? z : NEG_SLOPE * z; p += z * at4.x;
        z = a.y + xr4.y + cw * we4.y; z = (z > 0.f) ? z : NEG_SLOPE * z; p += z * at4.y;
        z = a.z + xr4.z + cw * we4.z; z = (z > 0.f) ? z : NEG_SLOPE * z; p += z * at4.z;
        z = a.w + xr4.w + cw * we4.w; z = (z > 0.f) ? z : NEG_SLOPE * z; p += z * at4.w;
        p += __shfl_xor(p, 1);
        p += __shfl_xor(p, 2);
        p += __shfl_xor(p, 4);
        float nm = fmaxf(m, p);
        float sc = __expf(m - nm);
        float pe = __expf(p - nm);
        d = d * sc + pe;
        acc.x = acc.x * sc + pe * a.x;
        acc.y = acc.y * sc + pe * a.y;
        acc.z = acc.z * sc + pe * a.z;
        acc.w = acc.w * sc + pe * a.w;
        m = nm;
    }
    float inv = 1.f / (d + 1e-16f);
    float4 b4 = ((const float4*)b2)[g];
    float vx = fmaxf(acc.x * inv + b4.x, 0.f);
    float vy = fmaxf(acc.y * inv + b4.y, 0.f);
    float vz = fmaxf(acc.z * inv + b4.z, 0.f);
    float vw = fmaxf(acc.w * inv + b4.w, 0.f);
    int b = batch[i];
    float* o = pool + (size_t)b * D_H + g * 4;
    atomicAdd(o + 0, vx);
    atomicAdd(o + 1, vy);
    atomicAdd(o + 2, vz);
    atomicAdd(o + 3, vw);
    if (g == 0) atomicAdd(&cnt[b], 1.0f);
}

// ---- mean, sigmoid, final FC ----
__global__ void k_final(const float* __restrict__ pool, const float* __restrict__ cnt,
                        const float* __restrict__ Wfc, const float* __restrict__ bfc,
                        float* __restrict__ out)
{
    int b = blockIdx.x * blockDim.x + threadIdx.x;
    if (b >= N_GRAPHS) return;
    float c = cnt[b]; c = c > 1.f ? c : 1.f;
    float acc = 0.f;
    #pragma unroll
    for (int j = 0; j < D_H; ++j) {
        float f = pool[b * D_H + j] / c;
        f = 1.f / (1.f + __expf(-f));
        acc += f * Wfc[j];
    }
    out[b] = acc + bfc[0];
}

extern "C" void kernel_launch(void* const* d_in, const int* in_sizes, int n_in,
                              void* d_out, int out_size, void* d_ws, size_t ws_size,
                              hipStream_t stream)
{
    const float* x    = (const float*)d_in[0];
    const int*   ei   = (const int*)  d_in[1];
    const int*   batch= (const int*)  d_in[2];
    const float* ew   = (const float*)d_in[3];
    const float* Wl1  = (const float*)d_in[4];
    const float* Wr1  = (const float*)d_in[5];
    const float* We1  = (const float*)d_in[6];
    const float* att1 = (const float*)d_in[7];
    const float* b1   = (const float*)d_in[8];
    const float* Wl2  = (const float*)d_in[9];
    const float* Wr2  = (const float*)d_in[10];
    const float* We2  = (const float*)d_in[11];
    const float* att2 = (const float*)d_in[12];
    const float* b2   = (const float*)d_in[13];
    const float* Wfc  = (const float*)d_in[14];
    const float* bfc  = (const float*)d_in[15];
    float* out = (float*)d_out;

    float* ws = (float*)d_ws;
    size_t off = 0;
    auto take = [&](size_t n) -> float* {
        float* p = ws + off;
        off = (off + n + 63) & ~(size_t)63;
        return p;
    };
    // --- zero-initialized region ---
    float* fillsum = take(1);
    int*   deg  = (int*)take(N_NODES);
    int*   cur  = (int*)take(N_NODES);
    float* cnt  = take(N_GRAPHS);
    float* pool = take((size_t)N_GRAPHS * D_H);
    size_t zero_elems = off;
    // --- written-before-read buffers (sizes in floats; bf16 = n/2 floats) ---
    int*   start   = (int*)take(N_NODES);
    int*   bsum    = (int*)take(256);
    int*   csr_src = (int*)take(E_TOT);
    float* csr_w   = take(E_TOT);
    unsigned short* xb   = (unsigned short*)take((size_t)N_NODES * D_IN / 2);
    unsigned short* Wt1  = (unsigned short*)take(512 * 128 / 2);
    unsigned short* Wt2  = (unsigned short*)take(64 * 256 / 2);
    unsigned short* xlr1 = (unsigned short*)take((size_t)N_NODES * 512 / 2);
    unsigned short* out1 = (unsigned short*)take((size_t)N_NODES * 256 / 2);
    unsigned short* xlr2 = (unsigned short*)take((size_t)N_NODES * 64 / 2);
    (void)ws_size; (void)in_sizes; (void)n_in; (void)out_size;

    hipMemsetAsync(d_ws, 0, zero_elems * sizeof(float), stream);

    // fill value = mean(edge_weight)
    k_reduce_sum<<<512, 256, 0, stream>>>(ew, fillsum, N_EDGES);

    // CSR build (destination-sorted)
    k_hist<<<(E_TOT + 255) / 256, 256, 0, stream>>>(ei, deg);
    k_scan1<<<NSCAN_BLK, 256, 0, stream>>>(deg, start, bsum);
    k_scan2<<<1, 256, 0, stream>>>(bsum, NSCAN_BLK);
    k_scan3<<<NSCAN_BLK, 256, 0, stream>>>(start, bsum);
    k_scatter<<<(E_TOT + 255) / 256, 256, 0, stream>>>(ei, ew, fillsum, start, cur, csr_src, csr_w);

    // bf16 prep
    k_cast_x<<<((size_t)N_NODES * D_IN / 4 + 255) / 256, 256, 0, stream>>>(x, xb, N_NODES * D_IN / 4);
    k_prep_w1<<<(512 * 128 + 255) / 256, 256, 0, stream>>>(Wl1, Wr1, Wt1);
    k_prep_w2<<<(64 * 256 + 255) / 256, 256, 0, stream>>>(Wl2, Wr2, Wt2);

    // layer-1 projection: xlr1 = xb @ [Wl1|Wr1]  (M=50000, N=512, K=128)
    k_gemm_bf16<128><<<dim3(512 / 64, (N_NODES + 63) / 64), 256, 0, stream>>>(
        xb, Wt1, xlr1, N_NODES, 512);

    // fused layer-1 edge phase
    k_gat1<<<(N_NODES * 64 + 255) / 256, 256, 0, stream>>>(
        xlr1, start, deg, csr_src, csr_w, We1, att1, b1, out1);

    // layer-2 projection: xlr2 = out1 @ [Wl2|Wr2]  (M=50000, N=64, K=256)
    k_gemm_bf16<256><<<dim3(64 / 64, (N_NODES + 63) / 64), 256, 0, stream>>>(
        out1, Wt2, xlr2, N_NODES, 64);

    // fused layer-2 edge phase + pooling
    k_gat2<<<((size_t)N_NODES * 8 + 255) / 256, 256, 0, stream>>>(
        xlr2, start, deg, csr_src, csr_w, We2, att2, b2, batch, pool, cnt);

    // final FC
    k_final<<<(N_GRAPHS + 255) / 256, 256, 0, stream>>>(pool, cnt, Wfc, bfc, out);
}